// Round 5
// baseline (91.288 us; speedup 1.0000x reference)
//
#include <hip/hip_runtime.h>
#include <hip/hip_bf16.h>

#define B_ 8
#define C_ 96
#define H_ 64
#define W_ 96
#define DD 21
#define NI 7               // i-values per block
#define ISPLIT 3           // 21 / NI
#define LDSTm 37           // Dst row stride (floats): 5 mod 32 -> conflict-light scatter
#define RAWS 49            // prep LDS row stride (uints): conflict-free gather

typedef __attribute__((ext_vector_type(8))) short sh8;
typedef __attribute__((ext_vector_type(4))) float fx4;

// Fragment-major bf16 tensors: innermost [lane(64)][e(8)] = 1KB per k-block,
// so a wave's MFMA operand load is base + lane*16B (fully coalesced).
// d1F: [b][y][p][ut(3)][k(3)][lane][8]
// d2F: [b][yp(104)][p][wt(5)][k(3)][lane][8]   (yp/x padded, borders zero)
__device__ __attribute__((aligned(16))) unsigned short g_d1F[B_*H_*2*3*3*512];
__device__ __attribute__((aligned(16))) unsigned short g_d2F[(size_t)B_*104*2*5*3*512];

// One fused prep kernel: grid (168, B).
//  t in [0,64):    d1 row y=t          -> g_d1F
//  t in [64,168):  d2 padded row yp=t-64 (zero-fill if border) -> g_d2F
__global__ __launch_bounds__(256) void prep_all(const float* __restrict__ d1,
                                                const float* __restrict__ d2) {
  __shared__ unsigned int raw[C_*RAWS];    // [c][w] packed (p0 | p1<<16)
  const int b = blockIdx.y;
  const int t = blockIdx.x;

  if (t >= 64) {
    const int yp = t - 64;
    unsigned short* ob = g_d2F + (size_t)(b*104 + yp)*(2*15*512);
    if (yp < 20 || yp >= 84) {             // border row: pure zero-fill
      uint4 z; z.x = z.y = z.z = z.w = 0u;
      for (int s = threadIdx.x; s < 1920; s += 256)
        *((uint4*)ob + s) = z;
      return;
    }
    const int y = yp - 20;
    for (int idx = threadIdx.x; idx < C_*48; idx += 256) {
      int c = idx / 48, w = idx % 48;
      const float2 v = *(const float2*)(d2 + (((b*C_ + c)*H_ + y)*W_ + 2*w));
      __hip_bfloat16 h0 = __float2bfloat16(v.x), h1 = __float2bfloat16(v.y);
      raw[c*RAWS + w] = (unsigned)*(unsigned short*)&h0 |
                        ((unsigned)*(unsigned short*)&h1 << 16);
    }
    __syncthreads();
    for (int s = threadIdx.x; s < 2*15*64; s += 256) {
      int lane = s & 63, q = s >> 6;
      int kk = q % 3, wt = (q/3) % 5, p = q / 15;
      int w = wt*16 + (lane & 15) - 10;    // x-pad: stored col = w' - 10
      int cb = kk*32 + (lane >> 4)*8;
      uint4 o; o.x = o.y = o.z = o.w = 0u;
      if (w >= 0 && w < 48) {
        unsigned short tmp[8];
        #pragma unroll
        for (int e = 0; e < 8; ++e) {
          unsigned pk = raw[(cb + e)*RAWS + w];
          tmp[e] = (unsigned short)(p ? (pk >> 16) : pk);
        }
        o = *(const uint4*)tmp;
      }
      *(uint4*)(ob + (size_t)s*8) = o;
    }
  } else {
    const int y = t;
    for (int idx = threadIdx.x; idx < C_*48; idx += 256) {
      int c = idx / 48, w = idx % 48;
      const float2 v = *(const float2*)(d1 + (((b*C_ + c)*H_ + y)*W_ + 2*w));
      __hip_bfloat16 h0 = __float2bfloat16(v.x), h1 = __float2bfloat16(v.y);
      raw[c*RAWS + w] = (unsigned)*(unsigned short*)&h0 |
                        ((unsigned)*(unsigned short*)&h1 << 16);
    }
    __syncthreads();
    unsigned short* ob = g_d1F + (size_t)(b*H_ + y)*(2*9*512);
    for (int s = threadIdx.x; s < 2*9*64; s += 256) {
      int lane = s & 63, q = s >> 6;
      int kk = q % 3, ut = (q/3) % 3, p = q / 9;
      int w = ut*16 + (lane & 15);
      int cb = kk*32 + (lane >> 4)*8;
      unsigned short tmp[8];
      #pragma unroll
      for (int e = 0; e < 8; ++e) {
        unsigned pk = raw[(cb + e)*RAWS + w];
        tmp[e] = (unsigned short)(p ? (pk >> 16) : pk);
      }
      *(uint4*)(ob + (size_t)s*8) = *(const uint4*)tmp;
    }
  }
}

// One block per (b, m-tile, y-pair, i-segment): 128 threads = 2 waves (p=0,1).
// y-pair = {y0, y0+2} (same parity): output (y,i) uses B row yp = y+2i, and
// rows for (y0, i) and (y0+2, i-1) coincide -> 8 B-row loads serve 14 GEMMs.
// Wave (p): A[u][c]=d1[b,c,y,2u+p], u in [m0,m0+16); B[w'][c]=d2pad[...,2w'+p].
// G=A·B^T band: out[b, i*21+j, y, 2u+p] = G[u, u+j], j in [0,21).
__global__ __launch_bounds__(128, 4) void corr_main(const float* __restrict__ s1,
                                                    const float* __restrict__ s2,
                                                    const float* __restrict__ os,
                                                    float* __restrict__ out) {
  __shared__ float Dst[2][DD*LDSTm];
  const int gid = blockIdx.x;
  const int b = gid & 7;                   // XCD affinity
  int t = gid >> 3;
  const int m0 = (t % 3) << 4; t /= 3;
  const int g = t & 31;                    // y-pair id
  const int i0 = (t >> 5) * NI;
  const int y0 = (g >> 1)*4 + (g & 1);     // pair = {y0, y0+2}, covers all 64 y
  const int p = threadIdx.x >> 6;
  const int lane = threadIdx.x & 63;
  const int lr = lane & 15, lg = lane >> 4;
  const float scale = s1[0]*s2[0] / (96.0f * os[0]);

  // A fragments for both y's of the pair (constant across i)
  sh8 aF[2][3];
  #pragma unroll
  for (int g2 = 0; g2 < 2; ++g2) {
    const unsigned short* aB =
        g_d1F + (size_t)((b*H_ + y0 + 2*g2)*2 + p)*(9*512) + (size_t)(m0 >> 4)*3*512 + lane*8;
    #pragma unroll
    for (int k = 0; k < 3; ++k)
      aF[g2][k] = *(const sh8*)(aB + k*512);
  }

  auto loadB = [&](sh8* bf, int row) {
    const unsigned short* rb =
        g_d2F + (size_t)(((b*104 + row)*2 + p)*5 + (m0 >> 4))*(3*512) + lane*8;
    #pragma unroll
    for (int n = 0; n < 3; ++n)
      #pragma unroll
      for (int k = 0; k < 3; ++k)
        bf[k*3+n] = *(const sh8*)(rb + (n*3 + k)*512);
  };

  auto combo = [&](const sh8* af, const sh8* bb, int y, int i, int buf) {
    fx4 acc[3] = {fx4{0,0,0,0}, fx4{0,0,0,0}, fx4{0,0,0,0}};
    #pragma unroll
    for (int k = 0; k < 3; ++k)
      #pragma unroll
      for (int n = 0; n < 3; ++n)
        acc[n] = __builtin_amdgcn_mfma_f32_16x16x32_bf16(af[k], bb[k*3+n], acc[n], 0, 0, 0);
    // band extract: col w' = m0+16n+lr, row u = m0+4lg+r ; j = w'-u, x = 2u+p
    #pragma unroll
    for (int n = 0; n < 3; ++n)
      #pragma unroll
      for (int r = 0; r < 4; ++r) {
        int j = 16*n + lr - 4*lg - r;
        if (j >= 0 && j < DD)
          Dst[buf][j*LDSTm + 2*(4*lg + r) + p] = acc[n][r];
      }
    __syncthreads();
    // store this block's 21 x 32 sub-plane (contiguous 128B rows)
    size_t obase = (size_t)((b*441 + i*DD)*H_ + y)*W_ + 2*m0;
    for (int s = threadIdx.x; s < DD*32; s += 128) {
      int j = s >> 5, xl = s & 31;
      out[obase + (size_t)j*(H_*W_) + xl] = Dst[buf][j*LDSTm + xl] * scale;
    }
    // no trailing barrier: ping-pong buffers; the next combo's barrier
    // (after its extract) orders buffer reuse. Race-free, 1 barrier/combo.
  };

  const int yr0 = y0 + 2*i0;               // first B row
  sh8 bA[9], bB[9];
  loadB(bA, yr0);
  int cnt = 0;
  #pragma unroll
  for (int d = 0; d < NI + 1; ++d) {       // 8 B rows
    sh8* cur = (d & 1) ? bB : bA;
    sh8* nxt = (d & 1) ? bA : bB;
    if (d < NI) loadB(nxt, yr0 + 2*(d + 1));
    if (d < NI)  { combo(aF[0], cur, y0,     i0 + d,     cnt & 1); ++cnt; }
    if (d >= 1)  { combo(aF[1], cur, y0 + 2, i0 + d - 1, cnt & 1); ++cnt; }
  }
}

extern "C" void kernel_launch(void* const* d_in, const int* in_sizes, int n_in,
                              void* d_out, int out_size, void* d_ws, size_t ws_size,
                              hipStream_t stream) {
  const float* d1 = (const float*)d_in[0];
  const float* d2 = (const float*)d_in[1];
  const float* s1 = (const float*)d_in[2];
  const float* s2 = (const float*)d_in[3];
  const float* os = (const float*)d_in[5];   // inter_scale (d_in[4]) unused

  prep_all<<<dim3(168, B_), 256, 0, stream>>>(d1, d2);
  corr_main<<<B_*3*32*ISPLIT, 128, 0, stream>>>(s1, s2, os, (float*)d_out);
}

// Round 6
// 53.080 us; speedup vs baseline: 1.7198x; 1.7198x over previous
//
#include <hip/hip_runtime.h>
#include <hip/hip_bf16.h>

#define B_ 8
#define C_ 96
#define H_ 64
#define W_ 96
#define DD 21
#define NI 7               // i-values per block (per y of the pair)
#define ISPLIT 3           // 21 / NI
#define LDSTm 37           // Dst row stride (floats): 5 mod 32 -> conflict-light scatter
#define RAWS 49            // prep LDS row stride (uints): conflict-free gather

typedef __attribute__((ext_vector_type(8))) short sh8;
typedef __attribute__((ext_vector_type(4))) float fx4;

// Fragment-major bf16 tensors: innermost [lane(64)][e(8)] = 1KB per k-block,
// so a wave's MFMA operand load is base + lane*16B (fully coalesced).
// d1F: [b][y][p][ut(3)][k(3)][lane][8]
// d2F: [b][yp(104)][p][wt(5)][k(3)][lane][8]   (yp/x padded, borders zero)
__device__ __attribute__((aligned(16))) unsigned short g_d1F[B_*H_*2*3*3*512];
__device__ __attribute__((aligned(16))) unsigned short g_d2F[(size_t)B_*104*2*5*3*512];

// One fused prep kernel: grid (168, B).
//  t in [0,64):    d1 row y=t          -> g_d1F
//  t in [64,168):  d2 padded row yp=t-64 (zero-fill if border) -> g_d2F
__global__ __launch_bounds__(256) void prep_all(const float* __restrict__ d1,
                                                const float* __restrict__ d2) {
  __shared__ unsigned int raw[C_*RAWS];    // [c][w] packed (p0 | p1<<16)
  const int b = blockIdx.y;
  const int t = blockIdx.x;

  if (t >= 64) {
    const int yp = t - 64;
    unsigned short* ob = g_d2F + (size_t)(b*104 + yp)*(2*15*512);
    if (yp < 20 || yp >= 84) {             // border row: pure zero-fill
      uint4 z; z.x = z.y = z.z = z.w = 0u;
      for (int s = threadIdx.x; s < 1920; s += 256)
        *((uint4*)ob + s) = z;
      return;
    }
    const int y = yp - 20;
    for (int idx = threadIdx.x; idx < C_*48; idx += 256) {
      int c = idx / 48, w = idx % 48;
      const float2 v = *(const float2*)(d2 + (((b*C_ + c)*H_ + y)*W_ + 2*w));
      __hip_bfloat16 h0 = __float2bfloat16(v.x), h1 = __float2bfloat16(v.y);
      raw[c*RAWS + w] = (unsigned)*(unsigned short*)&h0 |
                        ((unsigned)*(unsigned short*)&h1 << 16);
    }
    __syncthreads();
    for (int s = threadIdx.x; s < 2*15*64; s += 256) {
      int lane = s & 63, q = s >> 6;
      int kk = q % 3, wt = (q/3) % 5, p = q / 15;
      int w = wt*16 + (lane & 15) - 10;    // x-pad: stored col = w' - 10
      int cb = kk*32 + (lane >> 4)*8;
      uint4 o; o.x = o.y = o.z = o.w = 0u;
      if (w >= 0 && w < 48) {
        unsigned short tmp[8];
        #pragma unroll
        for (int e = 0; e < 8; ++e) {
          unsigned pk = raw[(cb + e)*RAWS + w];
          tmp[e] = (unsigned short)(p ? (pk >> 16) : pk);
        }
        o = *(const uint4*)tmp;
      }
      *(uint4*)(ob + (size_t)s*8) = o;
    }
  } else {
    const int y = t;
    for (int idx = threadIdx.x; idx < C_*48; idx += 256) {
      int c = idx / 48, w = idx % 48;
      const float2 v = *(const float2*)(d1 + (((b*C_ + c)*H_ + y)*W_ + 2*w));
      __hip_bfloat16 h0 = __float2bfloat16(v.x), h1 = __float2bfloat16(v.y);
      raw[c*RAWS + w] = (unsigned)*(unsigned short*)&h0 |
                        ((unsigned)*(unsigned short*)&h1 << 16);
    }
    __syncthreads();
    unsigned short* ob = g_d1F + (size_t)(b*H_ + y)*(2*9*512);
    for (int s = threadIdx.x; s < 2*9*64; s += 256) {
      int lane = s & 63, q = s >> 6;
      int kk = q % 3, ut = (q/3) % 3, p = q / 9;
      int w = ut*16 + (lane & 15);
      int cb = kk*32 + (lane >> 4)*8;
      unsigned short tmp[8];
      #pragma unroll
      for (int e = 0; e < 8; ++e) {
        unsigned pk = raw[(cb + e)*RAWS + w];
        tmp[e] = (unsigned short)(p ? (pk >> 16) : pk);
      }
      *(uint4*)(ob + (size_t)s*8) = *(const uint4*)tmp;
    }
  }
}

// ---- spill-proof building blocks for corr_main (no array-pointer params) ----
#define LOADB(ROW) do {                                                        \
    const unsigned short* rb =                                                 \
        g_d2F + (size_t)(((b*104 + (ROW))*2 + p)*5 + mt)*(3*512) + lane*8;     \
    _Pragma("unroll")                                                          \
    for (int n_ = 0; n_ < 3; ++n_)                                             \
      _Pragma("unroll")                                                        \
      for (int k_ = 0; k_ < 3; ++k_)                                           \
        bF[k_*3+n_] = *(const sh8*)(rb + (n_*3 + k_)*512);                     \
  } while (0)

#define COMBO(AF, Y, I, BUF) do {                                              \
    fx4 acc[3] = {fx4{0,0,0,0}, fx4{0,0,0,0}, fx4{0,0,0,0}};                   \
    _Pragma("unroll")                                                          \
    for (int k_ = 0; k_ < 3; ++k_)                                             \
      _Pragma("unroll")                                                        \
      for (int n_ = 0; n_ < 3; ++n_)                                           \
        acc[n_] = __builtin_amdgcn_mfma_f32_16x16x32_bf16(AF[k_], bF[k_*3+n_], \
                                                          acc[n_], 0, 0, 0);   \
    _Pragma("unroll")                                                          \
    for (int n_ = 0; n_ < 3; ++n_)                                             \
      _Pragma("unroll")                                                        \
      for (int r_ = 0; r_ < 4; ++r_) {                                         \
        int j_ = 16*n_ + lr - 4*lg - r_;                                       \
        if (j_ >= 0 && j_ < DD)                                                \
          Dst[BUF][j_*LDSTm + 2*(4*lg + r_) + p] = acc[n_][r_];                \
      }                                                                        \
    __syncthreads();                                                           \
    size_t obase = (size_t)((b*441 + (I)*DD)*H_ + (Y))*W_ + 2*m0;              \
    for (int s_ = threadIdx.x; s_ < DD*32; s_ += 128) {                        \
      int j_ = s_ >> 5, xl_ = s_ & 31;                                         \
      out[obase + (size_t)j_*(H_*W_) + xl_] = Dst[BUF][j_*LDSTm + xl_]*scale;  \
    }                                                                          \
  } while (0)
// No trailing barrier: combos strictly alternate Dst buffers; the next
// combo's barrier (after its extract) orders buffer reuse. Race-free.

// One block per (b, m-tile, y-pair, i-segment): 128 threads = 2 waves (p=0,1).
// y-pair = {y0, y0+2} (same parity): output (y,i) uses B row yp = y+2i, so
// rows for (y0, i) and (y0+2, i-1) coincide -> 8 B-row loads serve 14 GEMMs.
// Wave (p): A[u][c]=d1[b,c,y,2u+p], u in [m0,m0+16); B[w'][c]=d2pad[...,2w'+p].
// G=A·B^T band: out[b, i*21+j, y, 2u+p] = G[u, u+j], j in [0,21).
__global__ __launch_bounds__(128, 4) void corr_main(const float* __restrict__ s1,
                                                    const float* __restrict__ s2,
                                                    const float* __restrict__ os,
                                                    float* __restrict__ out) {
  __shared__ float Dst[2][DD*LDSTm];
  const int gid = blockIdx.x;
  const int b = gid & 7;                   // XCD affinity
  int t = gid >> 3;
  const int mt = t % 3; t /= 3;
  const int m0 = mt << 4;
  const int g = t & 31;                    // y-pair id
  const int i0 = (t >> 5) * NI;
  const int y0 = (g >> 1)*4 + (g & 1);     // pair = {y0, y0+2}, covers all 64 y
  const int p = threadIdx.x >> 6;
  const int lane = threadIdx.x & 63;
  const int lr = lane & 15, lg = lane >> 4;
  const float scale = s1[0]*s2[0] / (96.0f * os[0]);

  // A fragments for both y's of the pair (constant across i) — named arrays
  sh8 aF0[3], aF1[3];
  {
    const unsigned short* aB0 =
        g_d1F + (size_t)((b*H_ + y0)*2 + p)*(9*512) + (size_t)mt*3*512 + lane*8;
    const unsigned short* aB1 =
        g_d1F + (size_t)((b*H_ + y0 + 2)*2 + p)*(9*512) + (size_t)mt*3*512 + lane*8;
    #pragma unroll
    for (int k = 0; k < 3; ++k) {
      aF0[k] = *(const sh8*)(aB0 + k*512);
      aF1[k] = *(const sh8*)(aB1 + k*512);
    }
  }

  sh8 bF[9];
  const int yr0 = y0 + 2*i0;               // first B row
  int cnt = 0;
  for (int d = 0; d <= NI; ++d) {          // 8 B rows serve 14 combos
    LOADB(yr0 + 2*d);
    if (d < NI)  { COMBO(aF0, y0,     i0 + d,     cnt & 1); ++cnt; }
    if (d >= 1)  { COMBO(aF1, y0 + 2, i0 + d - 1, cnt & 1); ++cnt; }
  }
}

extern "C" void kernel_launch(void* const* d_in, const int* in_sizes, int n_in,
                              void* d_out, int out_size, void* d_ws, size_t ws_size,
                              hipStream_t stream) {
  const float* d1 = (const float*)d_in[0];
  const float* d2 = (const float*)d_in[1];
  const float* s1 = (const float*)d_in[2];
  const float* s2 = (const float*)d_in[3];
  const float* os = (const float*)d_in[5];   // inter_scale (d_in[4]) unused

  prep_all<<<dim3(168, B_), 256, 0, stream>>>(d1, d2);
  corr_main<<<B_*3*32*ISPLIT, 128, 0, stream>>>(s1, s2, os, (float*)d_out);
}

// Round 7
// 51.164 us; speedup vs baseline: 1.7842x; 1.0374x over previous
//
#include <hip/hip_runtime.h>
#include <hip/hip_bf16.h>

#define B_ 8
#define C_ 96
#define H_ 64
#define W_ 96
#define DD 21
#define NI 3               // i-values per block
#define ISPLIT 7           // 21 / NI
#define LDSTm 37           // Dst row stride (floats): 5 mod 32 -> conflict-light scatter
#define RAWS 49            // prep LDS row stride (uints): conflict-free gather

typedef __attribute__((ext_vector_type(8))) short sh8;
typedef __attribute__((ext_vector_type(4))) float fx4;

// Fragment-major bf16 tensors: innermost [lane(64)][e(8)] = 1KB per k-block,
// so a wave's MFMA operand load is base + lane*16B (fully coalesced).
// d1F: [b][y][p][ut(3)][k(3)][lane][8]
// d2F: [b][yp(104)][p][wt(5)][k(3)][lane][8]   (yp/x padded, borders zero)
__device__ __attribute__((aligned(16))) unsigned short g_d1F[B_*H_*2*3*3*512];
__device__ __attribute__((aligned(16))) unsigned short g_d2F[(size_t)B_*104*2*5*3*512];

// One fused prep kernel: grid (168, B).
//  t in [0,64):    d1 row y=t          -> g_d1F
//  t in [64,168):  d2 padded row yp=t-64 (zero-fill if border) -> g_d2F
__global__ __launch_bounds__(256) void prep_all(const float* __restrict__ d1,
                                                const float* __restrict__ d2) {
  __shared__ unsigned int raw[C_*RAWS];    // [c][w] packed (p0 | p1<<16)
  const int b = blockIdx.y;
  const int t = blockIdx.x;

  if (t >= 64) {
    const int yp = t - 64;
    unsigned short* ob = g_d2F + (size_t)(b*104 + yp)*(2*15*512);
    if (yp < 20 || yp >= 84) {             // border row: pure zero-fill
      uint4 z; z.x = z.y = z.z = z.w = 0u;
      for (int s = threadIdx.x; s < 1920; s += 256)
        *((uint4*)ob + s) = z;
      return;
    }
    const int y = yp - 20;
    for (int idx = threadIdx.x; idx < C_*48; idx += 256) {
      int c = idx / 48, w = idx % 48;
      const float2 v = *(const float2*)(d2 + (((b*C_ + c)*H_ + y)*W_ + 2*w));
      __hip_bfloat16 h0 = __float2bfloat16(v.x), h1 = __float2bfloat16(v.y);
      raw[c*RAWS + w] = (unsigned)*(unsigned short*)&h0 |
                        ((unsigned)*(unsigned short*)&h1 << 16);
    }
    __syncthreads();
    for (int s = threadIdx.x; s < 2*15*64; s += 256) {
      int lane = s & 63, q = s >> 6;
      int kk = q % 3, wt = (q/3) % 5, p = q / 15;
      int w = wt*16 + (lane & 15) - 10;    // x-pad: stored col = w' - 10
      int cb = kk*32 + (lane >> 4)*8;
      uint4 o; o.x = o.y = o.z = o.w = 0u;
      if (w >= 0 && w < 48) {
        unsigned short tmp[8];
        #pragma unroll
        for (int e = 0; e < 8; ++e) {
          unsigned pk = raw[(cb + e)*RAWS + w];
          tmp[e] = (unsigned short)(p ? (pk >> 16) : pk);
        }
        o = *(const uint4*)tmp;
      }
      *(uint4*)(ob + (size_t)s*8) = o;
    }
  } else {
    const int y = t;
    for (int idx = threadIdx.x; idx < C_*48; idx += 256) {
      int c = idx / 48, w = idx % 48;
      const float2 v = *(const float2*)(d1 + (((b*C_ + c)*H_ + y)*W_ + 2*w));
      __hip_bfloat16 h0 = __float2bfloat16(v.x), h1 = __float2bfloat16(v.y);
      raw[c*RAWS + w] = (unsigned)*(unsigned short*)&h0 |
                        ((unsigned)*(unsigned short*)&h1 << 16);
    }
    __syncthreads();
    unsigned short* ob = g_d1F + (size_t)(b*H_ + y)*(2*9*512);
    for (int s = threadIdx.x; s < 2*9*64; s += 256) {
      int lane = s & 63, q = s >> 6;
      int kk = q % 3, ut = (q/3) % 3, p = q / 9;
      int w = ut*16 + (lane & 15);
      int cb = kk*32 + (lane >> 4)*8;
      unsigned short tmp[8];
      #pragma unroll
      for (int e = 0; e < 8; ++e) {
        unsigned pk = raw[(cb + e)*RAWS + w];
        tmp[e] = (unsigned short)(p ? (pk >> 16) : pk);
      }
      *(uint4*)(ob + (size_t)s*8) = *(const uint4*)tmp;
    }
  }
}

// LDS-only barrier: orders extract(ds_write) -> store(ds_read) across the
// block WITHOUT draining vmcnt -- prefetched global loads stay in flight
// across the barrier (the compiler auto-waits the right vmcnt before the
// MFMAs that consume them). "memory" clobber pins LDS ops on both sides.
#define SYNC_LDS asm volatile("s_waitcnt lgkmcnt(0)\n\ts_barrier" ::: "memory")

// Token-pasting macros over NAMED register arrays (bF0/bF1): every array
// index is compile-time after unroll -> no scratch (rule #20; R5 lesson).
#define LOADB(BF, ROW) do {                                                    \
    const unsigned short* rb_ =                                                \
        g_d2F + (size_t)(((b*104 + (ROW))*2 + p)*5 + mt)*(3*512) + lane*8;     \
    _Pragma("unroll")                                                          \
    for (int n_ = 0; n_ < 3; ++n_)                                             \
      _Pragma("unroll")                                                        \
      for (int k_ = 0; k_ < 3; ++k_)                                           \
        BF[k_*3+n_] = *(const sh8*)(rb_ + (n_*3 + k_)*512);                    \
  } while (0)

#define COMBO(BF, I, BUF) do {                                                 \
    fx4 acc[3] = {fx4{0,0,0,0}, fx4{0,0,0,0}, fx4{0,0,0,0}};                   \
    _Pragma("unroll")                                                          \
    for (int k_ = 0; k_ < 3; ++k_)                                             \
      _Pragma("unroll")                                                        \
      for (int n_ = 0; n_ < 3; ++n_)                                           \
        acc[n_] = __builtin_amdgcn_mfma_f32_16x16x32_bf16(aF[k_], BF[k_*3+n_], \
                                                          acc[n_], 0, 0, 0);   \
    _Pragma("unroll")                                                          \
    for (int n_ = 0; n_ < 3; ++n_)                                             \
      _Pragma("unroll")                                                        \
      for (int r_ = 0; r_ < 4; ++r_) {                                         \
        int j_ = 16*n_ + lr - 4*lg - r_;                                       \
        if (j_ >= 0 && j_ < DD)                                                \
          Dst[BUF][j_*LDSTm + 2*(4*lg + r_) + p] = acc[n_][r_];                \
      }                                                                        \
    SYNC_LDS;                                                                  \
    size_t obase = (size_t)((b*441 + (I)*DD)*H_ + y)*W_ + 2*m0;                \
    for (int s_ = threadIdx.x; s_ < DD*32; s_ += 128) {                        \
      int j_ = s_ >> 5, xl_ = s_ & 31;                                         \
      out[obase + (size_t)j_*(H_*W_) + xl_] = Dst[BUF][j_*LDSTm + xl_]*scale;  \
    }                                                                          \
  } while (0)
// Dst ping-pong race check: extract into BUF happens only after the barrier
// that followed the previous store of the SAME buffer (two combos earlier)
// -- race-free with one LDS barrier per combo.

// One block per (b, m-tile, y, i-segment): 128 threads = 2 waves (p=0,1).
// Wave (p): A[u][c]=d1[b,c,y,2u+p], u in [m0,m0+16); B[w'][c]=d2pad[...,2w'+p].
// G=A·B^T band: out[b, i*21+j, y, 2u+p] = G[u, u+j], j in [0,21).
// B rows register-double-buffered: LOADB(next) issues before COMBO(cur), and
// SYNC_LDS lets those loads stay outstanding across the barrier.
__global__ __launch_bounds__(128, 4) void corr_main(const float* __restrict__ s1,
                                                    const float* __restrict__ s2,
                                                    const float* __restrict__ os,
                                                    float* __restrict__ out) {
  __shared__ float Dst[2][DD*LDSTm];
  const int gid = blockIdx.x;
  const int b = gid & 7;                   // XCD affinity
  int t = gid >> 3;
  const int mt = t % 3; t /= 3;
  const int m0 = mt << 4;
  const int y = t & 63;
  const int i0 = (t >> 6) * NI;
  const int p = threadIdx.x >> 6;
  const int lane = threadIdx.x & 63;
  const int lr = lane & 15, lg = lane >> 4;
  const float scale = s1[0]*s2[0] / (96.0f * os[0]);

  sh8 aF[3];
  {
    const unsigned short* aB =
        g_d1F + (size_t)((b*H_ + y)*2 + p)*(9*512) + (size_t)mt*3*512 + lane*8;
    #pragma unroll
    for (int k = 0; k < 3; ++k)
      aF[k] = *(const sh8*)(aB + k*512);
  }

  sh8 bF0[9], bF1[9];
  const int yb = y + 2*i0;                 // B row for i0 (rows step by 2)
  LOADB(bF0, yb);
  LOADB(bF1, yb + 2);
  COMBO(bF0, i0,     0);
  LOADB(bF0, yb + 4);
  COMBO(bF1, i0 + 1, 1);
  COMBO(bF0, i0 + 2, 0);
}

extern "C" void kernel_launch(void* const* d_in, const int* in_sizes, int n_in,
                              void* d_out, int out_size, void* d_ws, size_t ws_size,
                              hipStream_t stream) {
  const float* d1 = (const float*)d_in[0];
  const float* d2 = (const float*)d_in[1];
  const float* s1 = (const float*)d_in[2];
  const float* s2 = (const float*)d_in[3];
  const float* os = (const float*)d_in[5];   // inter_scale (d_in[4]) unused

  prep_all<<<dim3(168, B_), 256, 0, stream>>>(d1, d2);
  corr_main<<<B_*3*H_*ISPLIT, 128, 0, stream>>>(s1, s2, os, (float*)d_out);
}